// Round 1
// baseline (484.739 us; speedup 1.0000x reference)
//
#include <hip/hip_runtime.h>

#define B_DIM 16
#define U_DIM 1024
#define H_DIM 8
#define S_DIM 1024
#define C_DIM 128
#define KD 1024  // K depth of both projection GEMMs
#define SCALE 0.08838834764831845f  // 1/sqrt(128)

typedef __attribute__((ext_vector_type(8))) short s16x8;
typedef __attribute__((ext_vector_type(4))) float f32x4;

__device__ __forceinline__ void gll16(const void* g, void* l) {
  __builtin_amdgcn_global_load_lds(
      (const __attribute__((address_space(1))) unsigned int*)g,
      (__attribute__((address_space(3))) unsigned int*)l, 16, 0, 0);
}
__device__ __forceinline__ unsigned short f2bf(float f) {
  unsigned u = __float_as_uint(f);
  u += 0x7FFF + ((u >> 16) & 1u);
  return (unsigned short)(u >> 16);
}
#define MFMA16(a, b, c) __builtin_amdgcn_mfma_f32_16x16x32_bf16(a, b, c, 0, 0, 0)

// ---------------------------------------------------------------------------
// Mask storage detection (bool may arrive as u8 / i32 / f32). See R1 notes.
// ---------------------------------------------------------------------------
__global__ void detect_mask(const unsigned char* __restrict__ mask_raw, int* __restrict__ flag) {
  __shared__ int not01, notf;
  if (threadIdx.x == 0) { not01 = 0; notf = 0; }
  __syncthreads();
  const unsigned int* p = (const unsigned int*)mask_raw;
  int l01 = 0, lf = 0;
  for (int i = threadIdx.x; i < 4096; i += 256) {
    unsigned int v = p[i];
    if (v != 0u && v != 1u) l01 = 1;
    if (v != 0u && v != 0x3F800000u) lf = 1;
  }
  if (l01) atomicOr(&not01, 1);
  if (lf) atomicOr(&notf, 1);
  __syncthreads();
  if (threadIdx.x == 0) flag[0] = (!not01) ? 0 : ((!notf) ? 2 : 1);
}

// ---------------------------------------------------------------------------
// Pack mask into k-major bit-words: bits[kt][b][q], word = 64 k bits
// (k = kt*64 + bit). attn reads 16 consecutive u64s per 16 lanes (128B line).
// ---------------------------------------------------------------------------
__global__ __launch_bounds__(256) void pack_mask(const unsigned char* __restrict__ mask_raw,
                                                 const int* __restrict__ flag,
                                                 unsigned long long* __restrict__ bits) {
  __shared__ unsigned char tile[64][80];  // [q][k], pad 80 keeps 16B alignment
  const int t = threadIdx.x;
  const int kt = blockIdx.x * 64, qw = blockIdx.y, b = blockIdx.z;
  const int mk = flag[0];
  const int q = t >> 2, kbase = (t & 3) * 16;
  const size_t row = (size_t)(b * S_DIM + qw * 64 + q);
  if (mk == 1) {
    uint4 v = *(const uint4*)(mask_raw + (row << 10) + kt + kbase);
    *(uint4*)&tile[q][kbase] = v;
  } else if (mk == 0) {
    const int* p = (const int*)mask_raw + (row << 10) + kt + kbase;
#pragma unroll
    for (int j = 0; j < 4; ++j) {
      int4 v = ((const int4*)p)[j];
      uchar4 o;
      o.x = v.x ? 1 : 0; o.y = v.y ? 1 : 0; o.z = v.z ? 1 : 0; o.w = v.w ? 1 : 0;
      *(uchar4*)&tile[q][kbase + j * 4] = o;
    }
  } else {
    const float* p = (const float*)mask_raw + (row << 10) + kt + kbase;
#pragma unroll
    for (int j = 0; j < 4; ++j) {
      float4 v = ((const float4*)p)[j];
      uchar4 o;
      o.x = (v.x != 0.f) ? 1 : 0; o.y = (v.y != 0.f) ? 1 : 0;
      o.z = (v.z != 0.f) ? 1 : 0; o.w = (v.w != 0.f) ? 1 : 0;
      *(uchar4*)&tile[q][kbase + j * 4] = o;
    }
  }
  __syncthreads();
  const int wave = t >> 6, lane = t & 63;
  // ballot along k: word = 64 k-bits at fixed q
#pragma unroll
  for (int qq = 0; qq < 16; ++qq) {
    int qr = wave * 16 + qq;
    unsigned long long bal = __ballot(tile[qr][lane] != 0);
    if (lane == 0)
      bits[(size_t)blockIdx.x * (B_DIM * S_DIM) + (size_t)b * S_DIM + qw * 64 + qr] = bal;
  }
}

// invm from packed bits: rowsum = sum_kt popcount(bits[kt][b][q])
__global__ __launch_bounds__(256) void invm_from_bits(const unsigned long long* __restrict__ bits,
                                                      float* __restrict__ invm) {
  int idx = blockIdx.x * 256 + threadIdx.x;  // = b*S + q
  int s = 0;
#pragma unroll
  for (int kt = 0; kt < S_DIM / 64; ++kt)
    s += __popcll(bits[(size_t)kt * (B_DIM * S_DIM) + idx]);
  invm[idx] = (s > 0) ? (SCALE / (float)s) : 0.f;
}

// fp32 -> bf16 elementwise (weights)
__global__ __launch_bounds__(256) void cvt_bf16(const float* __restrict__ in,
                                                unsigned short* __restrict__ out, int n) {
  int i = (blockIdx.x * 256 + threadIdx.x) * 4;
  if (i < n) {
    float4 v = *(const float4*)(in + i);
    ushort4 o;
    o.x = f2bf(v.x); o.y = f2bf(v.y); o.z = f2bf(v.z); o.w = f2bf(v.w);
    *(ushort4*)(out + i) = o;
  }
}

// x[b][u][s] f32 -> xT[b][s][u] bf16   (32x32 tiles)
__global__ __launch_bounds__(256) void transpose_x(const float* __restrict__ x,
                                                   unsigned short* __restrict__ xT) {
  __shared__ float T[32][33];
  const int t = threadIdx.x, r = t >> 3, c4 = (t & 7) * 4;
  const int s0 = blockIdx.x * 32, u0 = blockIdx.y * 32;
  const size_t base = (size_t)blockIdx.z * U_DIM * S_DIM;
  float4 v = *(const float4*)(x + base + (size_t)(u0 + r) * S_DIM + s0 + c4);
  T[r][c4 + 0] = v.x; T[r][c4 + 1] = v.y; T[r][c4 + 2] = v.z; T[r][c4 + 3] = v.w;
  __syncthreads();
  ushort4 o;
  o.x = f2bf(T[c4 + 0][r]); o.y = f2bf(T[c4 + 1][r]);
  o.z = f2bf(T[c4 + 2][r]); o.w = f2bf(T[c4 + 3][r]);
  *(ushort4*)(xT + base + (size_t)(s0 + r) * U_DIM + u0 + c4) = o;
}

// qkvT[b][k][2048+c] bf16 -> VT[b][c][k] bf16  (32x32 tiles)
__global__ __launch_bounds__(256) void transpose_v(const unsigned short* __restrict__ qkvT,
                                                   unsigned short* __restrict__ VT) {
  __shared__ unsigned short T[32][34];
  const int t = threadIdx.x, r = t >> 3, c4 = (t & 7) * 4;
  const int k0 = blockIdx.x * 32, c0 = blockIdx.y * 32;
  const unsigned short* qb = qkvT + (size_t)blockIdx.z * S_DIM * (3 * U_DIM);
  ushort4 v = *(const ushort4*)(qb + (size_t)(k0 + r) * (3 * U_DIM) + 2 * U_DIM + c0 + c4);
  T[r][c4 + 0] = v.x; T[r][c4 + 1] = v.y; T[r][c4 + 2] = v.z; T[r][c4 + 3] = v.w;
  __syncthreads();
  ushort4 o;
  o.x = T[c4 + 0][r]; o.y = T[c4 + 1][r]; o.z = T[c4 + 2][r]; o.w = T[c4 + 3][r];
  *(ushort4*)(VT + (size_t)blockIdx.z * U_DIM * S_DIM + (size_t)(c0 + r) * S_DIM + k0 + c4) = o;
}

// ---------------------------------------------------------------------------
// bf16 MFMA GEMM, BK=64 (32 KB LDS): halved barrier count vs BK=32, 32 MFMA
// per staging barrier (AITER-like cadence). XOR-swizzled 16B chunks.
//   D[m][n] = sum_k A[m][k] * B[n][k];  A,B row-major with K=1024 contiguous.
// XCD-aware bijective blockIdx swizzle: consecutive logical blocks (which
// share the A m-panel) are chunked onto one XCD's L2.
// ---------------------------------------------------------------------------
template <typename OUT>
__global__ __launch_bounds__(256) void gemm_tt(const unsigned short* __restrict__ A,
                                               const unsigned short* __restrict__ Bm,
                                               OUT* __restrict__ D,
                                               long long sAb, long long sBb, long long sDb,
                                               int N) {
  __shared__ unsigned short sA[128 * 64];
  __shared__ unsigned short sB[128 * 64];
  const int tid = threadIdx.x, wave = tid >> 6, lane = tid & 63;
  const int l15 = lane & 15, quad = lane >> 4;
  // bijective XCD swizzle (nwg % 8 == 0 at all call sites)
  const unsigned int Lb = blockIdx.x + gridDim.x * (blockIdx.y + gridDim.y * blockIdx.z);
  const unsigned int nwg = gridDim.x * gridDim.y * gridDim.z;
  const unsigned int logical = (Lb & 7u) * (nwg >> 3) + (Lb >> 3);
  const int bx = logical % gridDim.x;
  const unsigned int rem = logical / gridDim.x;
  const int by = rem % gridDim.y;
  const int bz = rem / gridDim.y;
  const int m0 = by * 128, n0 = bx * 128;
  A += (size_t)bz * sAb;
  Bm += (size_t)bz * sBb;
  D += (size_t)bz * sDb;
  const int wm = (wave >> 1) * 64, wn = (wave & 1) * 64;
  f32x4 acc[4][4] = {};

  for (int k0 = 0; k0 < KD; k0 += 64) {
#pragma unroll
    for (int t = 0; t < 4; ++t) {
      int p = wave * 256 + t * 64 + lane;
      int row = p >> 3, kc = (p & 7) ^ (row & 7);
      gll16(A + (size_t)(m0 + row) * KD + k0 + kc * 8, &sA[(wave * 256 + t * 64) * 8]);
    }
#pragma unroll
    for (int t = 0; t < 4; ++t) {
      int p = wave * 256 + t * 64 + lane;
      int row = p >> 3, kc = (p & 7) ^ (row & 7);
      gll16(Bm + (size_t)(n0 + row) * KD + k0 + kc * 8, &sB[(wave * 256 + t * 64) * 8]);
    }
    __syncthreads();
#pragma unroll
    for (int kk = 0; kk < 2; ++kk) {
      s16x8 af[4], bf[4];
#pragma unroll
      for (int i = 0; i < 4; ++i) {
        int row = wm + i * 16 + l15;
        af[i] = *(const s16x8*)&sA[row * 64 + ((kk * 4 + quad) ^ (row & 7)) * 8];
      }
#pragma unroll
      for (int j = 0; j < 4; ++j) {
        int row = wn + j * 16 + l15;
        bf[j] = *(const s16x8*)&sB[row * 64 + ((kk * 4 + quad) ^ (row & 7)) * 8];
      }
#pragma unroll
      for (int i = 0; i < 4; ++i)
#pragma unroll
        for (int j = 0; j < 4; ++j) acc[i][j] = MFMA16(af[i], bf[j], acc[i][j]);
    }
    __syncthreads();
  }
#pragma unroll
  for (int i = 0; i < 4; ++i)
#pragma unroll
    for (int j = 0; j < 4; ++j) {
      f32x4 v = acc[i][j];
#pragma unroll
      for (int r = 0; r < 4; ++r) {
        int m = m0 + wm + i * 16 + quad * 4 + r;
        int n = n0 + wn + j * 16 + l15;
        if constexpr (sizeof(OUT) == 2) D[(size_t)m * N + n] = f2bf(v[r]);
        else D[(size_t)m * N + n] = v[r];
      }
    }
}

// ---------------------------------------------------------------------------
// Fused masked-relu attention, 2-barrier pipelined K-loop.
// Dead Q staging buffer doubles as V ping-pong; K(t+1)/V(t+1) staging issued
// after the P-ready barrier so it overlaps PV compute. Occ 2 (L2-friendly).
// R(this): XCD swizzle co-locates each (b,h)'s 16 q-tiles on one XCD so the
// shared K/V panels (512 KB) L2-hit; P-pack via v_cvt_pk_bf16_f32; setprio
// around MFMA clusters.
// ---------------------------------------------------------------------------
__global__ __launch_bounds__(256, 2) void attn_mfma(const unsigned short* __restrict__ qkvT,
                                                    const unsigned short* __restrict__ VT,
                                                    const unsigned long long* __restrict__ bits,
                                                    const float* __restrict__ invm,
                                                    unsigned short* __restrict__ CcT, int b0) {
  __shared__ unsigned short QV[64 * 128];  // Q staging, then V ping buf (16 KB)
  __shared__ unsigned short Ks[64 * 128];  // [k][c] swizzled (16 KB)
  __shared__ unsigned short Vs[128 * 64];  // [c][k] swizzled (16 KB)
  __shared__ unsigned short Ps[64 * 64];   // [q][k] swizzled (8 KB)
  __shared__ float invs[64];

  const int tid = threadIdx.x, wave = tid >> 6, lane = tid & 63;
  const int l15 = lane & 15, quad = lane >> 4;
  // bijective XCD swizzle: nwg = 128*gridDim.z, always % 8 == 0.
  // XCD x gets logical blocks [x*cpx, (x+1)*cpx): 16*cnt consecutive
  // q-tiles => whole (b,h) groups stay on one XCD's L2.
  const int L = blockIdx.x + 16 * (blockIdx.y + 8 * blockIdx.z);
  const int cpx = (16 * H_DIM * gridDim.z) >> 3;
  const int logical = (L & 7) * cpx + (L >> 3);
  const int qt = logical & 15, h = (logical >> 4) & 7, z = logical >> 7;
  const int q0 = qt * 64, b = b0 + z;
  const unsigned short* qB = qkvT + (size_t)z * S_DIM * (3 * U_DIM);
  const unsigned short* Vb = VT + (size_t)z * U_DIM * S_DIM + (size_t)h * C_DIM * S_DIM;

  // prologue: stage Q -> QV, K(0) -> Ks, V(0) -> Vs
#pragma unroll
  for (int t = 0; t < 4; ++t) {
    int p = wave * 256 + t * 64 + lane;
    int row = p >> 4, c = (p & 15) ^ (row & 7);
    gll16(qB + (size_t)(q0 + row) * (3 * U_DIM) + h * C_DIM + c * 8,
          &QV[(wave * 256 + t * 64) * 8]);
    gll16(qB + (size_t)(row) * (3 * U_DIM) + U_DIM + h * C_DIM + c * 8,
          &Ks[(wave * 256 + t * 64) * 8]);
    int vrow = p >> 3, vkc = (p & 7) ^ (vrow & 7);
    gll16(Vb + (size_t)vrow * S_DIM + vkc * 8, &Vs[(wave * 256 + t * 64) * 8]);
  }
  if (tid < 64) invs[tid] = invm[(size_t)b * S_DIM + q0 + tid];
  __syncthreads();

  // Q fragments (B-operand: rows j*16+l15) + invm scalars to registers.
  // QV is dead after this point for all waves by the first P-ready barrier.
  s16x8 qf[4][4];
#pragma unroll
  for (int j = 0; j < 4; ++j)
#pragma unroll
    for (int kk = 0; kk < 4; ++kk) {
      int row = j * 16 + l15;
      qf[j][kk] = *(const s16x8*)&QV[row * 128 + ((kk * 4 + quad) ^ (row & 7)) * 8];
    }
  float invf[4];
#pragma unroll
  for (int j = 0; j < 4; ++j) invf[j] = invs[j * 16 + l15];

  f32x4 pacc[4][2] = {};

  for (int kt = 0; kt < S_DIM / 64; ++kt) {
    // mask words: 64 k-bits at q = q0 + j*16 + l15 (coalesced 128B per j)
    unsigned long long w64[4];
    {
      const unsigned long long* mw =
          bits + (size_t)kt * (B_DIM * S_DIM) + (size_t)b * S_DIM + q0;
#pragma unroll
      for (int j = 0; j < 4; ++j) w64[j] = mw[j * 16 + l15];
    }

    // scores D[k][q]: wave handles k rows [wave*16, wave*16+16), all 64 q
    s16x8 af[4];
#pragma unroll
    for (int kk = 0; kk < 4; ++kk) {
      int row = wave * 16 + l15;
      af[kk] = *(const s16x8*)&Ks[row * 128 + ((kk * 4 + quad) ^ (row & 7)) * 8];
    }
    f32x4 sacc[4] = {};
    __builtin_amdgcn_s_setprio(1);
#pragma unroll
    for (int kk = 0; kk < 4; ++kk)
#pragma unroll
      for (int j = 0; j < 4; ++j) sacc[j] = MFMA16(af[kk], qf[j][kk], sacc[j]);
    __builtin_amdgcn_s_setprio(0);

    // P = maskbit * relu(s) * scale/m -> packed bf16 via v_cvt_pk_bf16_f32
    // (RNE, matches f2bf) -> LDS b64. Mask: one 64-bit shift per j, then
    // 4-bit extracts (was: 64-bit shift per element + manual RNE pack).
#pragma unroll
    for (int j = 0; j < 4; ++j) {
      const unsigned int m4 = (unsigned int)(w64[j] >> (wave * 16 + quad * 4)) & 0xFu;
      float p[4];
#pragma unroll
      for (int r = 0; r < 4; ++r) {
        float t = fmaxf(sacc[j][r], 0.f) * invf[j];
        p[r] = ((m4 >> r) & 1u) ? t : 0.f;
      }
      unsigned int pk0, pk1;
      asm("v_cvt_pk_bf16_f32 %0, %1, %2" : "=v"(pk0) : "v"(p[0]), "v"(p[1]));
      asm("v_cvt_pk_bf16_f32 %0, %1, %2" : "=v"(pk1) : "v"(p[2]), "v"(p[3]));
      int q = j * 16 + l15;
      int chunk = (wave * 2 + (quad >> 1)) ^ (q & 7);
      *(uint2*)&Ps[q * 64 + chunk * 8 + (quad & 1) * 4] = make_uint2(pk0, pk1);
    }
    __syncthreads();  // P ready; all waves done reading Ks (and QV on kt==0)

    // overlap: stage K(t+1)->Ks, V(t+1)->other buf while PV computes
    if (kt < S_DIM / 64 - 1) {
      const int kn = (kt + 1) * 64;
      unsigned short* vdst = (kt & 1) ? Vs : QV;
#pragma unroll
      for (int t = 0; t < 4; ++t) {
        int p = wave * 256 + t * 64 + lane;
        int row = p >> 4, c = (p & 15) ^ (row & 7);
        gll16(qB + (size_t)(kn + row) * (3 * U_DIM) + U_DIM + h * C_DIM + c * 8,
              &Ks[(wave * 256 + t * 64) * 8]);
        int vrow = p >> 3, vkc = (p & 7) ^ (vrow & 7);
        gll16(Vb + (size_t)vrow * S_DIM + kn + vkc * 8, &vdst[(wave * 256 + t * 64) * 8]);
      }
    }

    // PV from V(kt) (even -> Vs, odd -> QV): wave c-cols [wave*32, +32)
    const unsigned short* vbuf = (kt & 1) ? QV : Vs;
#pragma unroll
    for (int ks = 0; ks < 2; ++ks) {
      s16x8 pf[4], vf[2];
#pragma unroll
      for (int i = 0; i < 4; ++i) {
        int row = i * 16 + l15;
        pf[i] = *(const s16x8*)&Ps[row * 64 + ((ks * 4 + quad) ^ (row & 7)) * 8];
      }
#pragma unroll
      for (int j = 0; j < 2; ++j) {
        int row = wave * 32 + j * 16 + l15;
        vf[j] = *(const s16x8*)&vbuf[row * 64 + ((ks * 4 + quad) ^ (row & 7)) * 8];
      }
      __builtin_amdgcn_s_setprio(1);
#pragma unroll
      for (int i = 0; i < 4; ++i)
#pragma unroll
        for (int j = 0; j < 2; ++j) pacc[i][j] = MFMA16(pf[i], vf[j], pacc[i][j]);
      __builtin_amdgcn_s_setprio(0);
    }
    __syncthreads();  // PV done + staging drained (vmcnt(0) at barrier)
  }

  // epilogue: CcT[b][q][h*128+c] bf16
  unsigned short* cb = CcT + (size_t)z * S_DIM * U_DIM;
#pragma unroll
  for (int i = 0; i < 4; ++i)
#pragma unroll
    for (int j = 0; j < 2; ++j) {
      f32x4 v = pacc[i][j];
#pragma unroll
      for (int r = 0; r < 4; ++r) {
        int q = q0 + i * 16 + quad * 4 + r;
        int c = h * C_DIM + wave * 32 + j * 16 + l15;
        cb[(size_t)q * U_DIM + c] = f2bf(v[r]);
      }
    }
}

// ---------------------------------------------------------------------------
extern "C" void kernel_launch(void* const* d_in, const int* in_sizes, int n_in,
                              void* d_out, int out_size, void* d_ws, size_t ws_size,
                              hipStream_t stream) {
  const float* x = (const float*)d_in[0];
  const unsigned char* mask_raw = (const unsigned char*)d_in[1];
  const float* w_qkv = (const float*)d_in[2];
  const float* w_out = (const float*)d_in[3];
  float* out = (float*)d_out;

  char* ws = (char*)d_ws;
  int* flag = (int*)ws;                                  // 256 B
  float* invm = (float*)(ws + 256);                      // 64 KB
  unsigned long long* bits = (unsigned long long*)(ws + 256 + 65536);  // 2 MB
  unsigned short* wqkv_bf = (unsigned short*)((char*)bits + (size_t)B_DIM * S_DIM * 16 * 8);
  unsigned short* wout_bf = (unsigned short*)((char*)wqkv_bf + (size_t)3 * U_DIM * U_DIM * 2);
  char* heap = (char*)wout_bf + (size_t)U_DIM * U_DIM * 2;

  const size_t xT_pb = (size_t)U_DIM * S_DIM * 2;
  const size_t qkvT_pb = (size_t)3 * U_DIM * S_DIM * 2;
  const size_t vT_pb = (size_t)U_DIM * S_DIM * 2;
  const size_t ccT_pb = (size_t)U_DIM * S_DIM * 2;
  const size_t per_batch = xT_pb + qkvT_pb + vT_pb + ccT_pb;  // 12.58 MB
  const size_t fixed = (size_t)(heap - ws);
  int nb = (ws_size > fixed) ? (int)((ws_size - fixed) / per_batch) : 1;
  if (nb < 1) nb = 1;
  if (nb > B_DIM) nb = B_DIM;

  unsigned short* xT = (unsigned short*)heap;
  unsigned short* qkvT = (unsigned short*)(heap + (size_t)nb * xT_pb);
  unsigned short* VT = (unsigned short*)(heap + (size_t)nb * (xT_pb + qkvT_pb));
  unsigned short* CcT = (unsigned short*)(heap + (size_t)nb * (xT_pb + qkvT_pb + vT_pb));

  detect_mask<<<1, 256, 0, stream>>>(mask_raw, flag);
  pack_mask<<<dim3(S_DIM / 64, S_DIM / 64, B_DIM), 256, 0, stream>>>(mask_raw, flag, bits);
  invm_from_bits<<<(B_DIM * S_DIM) / 256, 256, 0, stream>>>(bits, invm);
  cvt_bf16<<<(3 * U_DIM * U_DIM) / 1024, 256, 0, stream>>>(w_qkv, wqkv_bf, 3 * U_DIM * U_DIM);
  cvt_bf16<<<(U_DIM * U_DIM) / 1024, 256, 0, stream>>>(w_out, wout_bf, U_DIM * U_DIM);

  for (int b0 = 0; b0 < B_DIM; b0 += nb) {
    int cnt = (B_DIM - b0 < nb) ? (B_DIM - b0) : nb;
    transpose_x<<<dim3(S_DIM / 32, U_DIM / 32, cnt), 256, 0, stream>>>(
        x + (size_t)b0 * U_DIM * S_DIM, xT);
    gemm_tt<unsigned short><<<dim3(3 * U_DIM / 128, S_DIM / 128, cnt), 256, 0, stream>>>(
        xT, wqkv_bf, qkvT, (long long)U_DIM * S_DIM, 0LL, (long long)3 * U_DIM * S_DIM, 3 * U_DIM);
    transpose_v<<<dim3(S_DIM / 32, U_DIM / 32, cnt), 256, 0, stream>>>(qkvT, VT);
    attn_mfma<<<dim3(S_DIM / 64, H_DIM, cnt), 256, 0, stream>>>(
        qkvT, VT, bits, invm, CcT, b0);
    gemm_tt<float><<<dim3(S_DIM / 128, U_DIM / 128, cnt), 256, 0, stream>>>(
        wout_bf, CcT, out + (size_t)b0 * U_DIM * S_DIM, 0LL,
        (long long)U_DIM * S_DIM, (long long)U_DIM * S_DIM, S_DIM);
  }
}

// Round 2
// 465.027 us; speedup vs baseline: 1.0424x; 1.0424x over previous
//
#include <hip/hip_runtime.h>

#define B_DIM 16
#define U_DIM 1024
#define H_DIM 8
#define S_DIM 1024
#define C_DIM 128
#define KD 1024  // K depth of both projection GEMMs
#define SCALE 0.08838834764831845f  // 1/sqrt(128)

typedef __attribute__((ext_vector_type(8))) short s16x8;
typedef __attribute__((ext_vector_type(4))) float f32x4;

__device__ __forceinline__ void gll16(const void* g, void* l) {
  __builtin_amdgcn_global_load_lds(
      (const __attribute__((address_space(1))) unsigned int*)g,
      (__attribute__((address_space(3))) unsigned int*)l, 16, 0, 0);
}
__device__ __forceinline__ unsigned short f2bf(float f) {
  unsigned u = __float_as_uint(f);
  u += 0x7FFF + ((u >> 16) & 1u);
  return (unsigned short)(u >> 16);
}
#define MFMA16(a, b, c) __builtin_amdgcn_mfma_f32_16x16x32_bf16(a, b, c, 0, 0, 0)

// ---------------------------------------------------------------------------
// Mask storage detection (bool may arrive as u8 / i32 / f32).
// ---------------------------------------------------------------------------
__global__ void detect_mask(const unsigned char* __restrict__ mask_raw, int* __restrict__ flag) {
  __shared__ int not01, notf;
  if (threadIdx.x == 0) { not01 = 0; notf = 0; }
  __syncthreads();
  const unsigned int* p = (const unsigned int*)mask_raw;
  int l01 = 0, lf = 0;
  for (int i = threadIdx.x; i < 4096; i += 256) {
    unsigned int v = p[i];
    if (v != 0u && v != 1u) l01 = 1;
    if (v != 0u && v != 0x3F800000u) lf = 1;
  }
  if (l01) atomicOr(&not01, 1);
  if (lf) atomicOr(&notf, 1);
  __syncthreads();
  if (threadIdx.x == 0) flag[0] = (!not01) ? 0 : ((!notf) ? 2 : 1);
}

// ---------------------------------------------------------------------------
// Pack mask into k-major bit-words: bits[kt][b][q], word = 64 k bits.
// ---------------------------------------------------------------------------
__global__ __launch_bounds__(256) void pack_mask(const unsigned char* __restrict__ mask_raw,
                                                 const int* __restrict__ flag,
                                                 unsigned long long* __restrict__ bits) {
  __shared__ unsigned char tile[64][80];  // [q][k], pad 80 keeps 16B alignment
  const int t = threadIdx.x;
  const int kt = blockIdx.x * 64, qw = blockIdx.y, b = blockIdx.z;
  const int mk = flag[0];
  const int q = t >> 2, kbase = (t & 3) * 16;
  const size_t row = (size_t)(b * S_DIM + qw * 64 + q);
  if (mk == 1) {
    uint4 v = *(const uint4*)(mask_raw + (row << 10) + kt + kbase);
    *(uint4*)&tile[q][kbase] = v;
  } else if (mk == 0) {
    const int* p = (const int*)mask_raw + (row << 10) + kt + kbase;
#pragma unroll
    for (int j = 0; j < 4; ++j) {
      int4 v = ((const int4*)p)[j];
      uchar4 o;
      o.x = v.x ? 1 : 0; o.y = v.y ? 1 : 0; o.z = v.z ? 1 : 0; o.w = v.w ? 1 : 0;
      *(uchar4*)&tile[q][kbase + j * 4] = o;
    }
  } else {
    const float* p = (const float*)mask_raw + (row << 10) + kt + kbase;
#pragma unroll
    for (int j = 0; j < 4; ++j) {
      float4 v = ((const float4*)p)[j];
      uchar4 o;
      o.x = (v.x != 0.f) ? 1 : 0; o.y = (v.y != 0.f) ? 1 : 0;
      o.z = (v.z != 0.f) ? 1 : 0; o.w = (v.w != 0.f) ? 1 : 0;
      *(uchar4*)&tile[q][kbase + j * 4] = o;
    }
  }
  __syncthreads();
  const int wave = t >> 6, lane = t & 63;
#pragma unroll
  for (int qq = 0; qq < 16; ++qq) {
    int qr = wave * 16 + qq;
    unsigned long long bal = __ballot(tile[qr][lane] != 0);
    if (lane == 0)
      bits[(size_t)blockIdx.x * (B_DIM * S_DIM) + (size_t)b * S_DIM + qw * 64 + qr] = bal;
  }
}

// invm from packed bits: rowsum = sum_kt popcount(bits[kt][b][q])
__global__ __launch_bounds__(256) void invm_from_bits(const unsigned long long* __restrict__ bits,
                                                      float* __restrict__ invm) {
  int idx = blockIdx.x * 256 + threadIdx.x;  // = b*S + q
  int s = 0;
#pragma unroll
  for (int kt = 0; kt < S_DIM / 64; ++kt)
    s += __popcll(bits[(size_t)kt * (B_DIM * S_DIM) + idx]);
  invm[idx] = (s > 0) ? (SCALE / (float)s) : 0.f;
}

// fp32 -> bf16 elementwise (weights)
__global__ __launch_bounds__(256) void cvt_bf16(const float* __restrict__ in,
                                                unsigned short* __restrict__ out, int n) {
  int i = (blockIdx.x * 256 + threadIdx.x) * 4;
  if (i < n) {
    float4 v = *(const float4*)(in + i);
    ushort4 o;
    o.x = f2bf(v.x); o.y = f2bf(v.y); o.z = f2bf(v.z); o.w = f2bf(v.w);
    *(ushort4*)(out + i) = o;
  }
}

// x[b][u][s] f32 -> xT[b][s][u] bf16   (32x32 tiles)
__global__ __launch_bounds__(256) void transpose_x(const float* __restrict__ x,
                                                   unsigned short* __restrict__ xT) {
  __shared__ float T[32][33];
  const int t = threadIdx.x, r = t >> 3, c4 = (t & 7) * 4;
  const int s0 = blockIdx.x * 32, u0 = blockIdx.y * 32;
  const size_t base = (size_t)blockIdx.z * U_DIM * S_DIM;
  float4 v = *(const float4*)(x + base + (size_t)(u0 + r) * S_DIM + s0 + c4);
  T[r][c4 + 0] = v.x; T[r][c4 + 1] = v.y; T[r][c4 + 2] = v.z; T[r][c4 + 3] = v.w;
  __syncthreads();
  ushort4 o;
  o.x = f2bf(T[c4 + 0][r]); o.y = f2bf(T[c4 + 1][r]);
  o.z = f2bf(T[c4 + 2][r]); o.w = f2bf(T[c4 + 3][r]);
  *(ushort4*)(xT + base + (size_t)(s0 + r) * U_DIM + u0 + c4) = o;
}

// qkvT[b][k][2048+c] bf16 -> VT[b][c][k] bf16  (32x32 tiles)
__global__ __launch_bounds__(256) void transpose_v(const unsigned short* __restrict__ qkvT,
                                                   unsigned short* __restrict__ VT) {
  __shared__ unsigned short T[32][34];
  const int t = threadIdx.x, r = t >> 3, c4 = (t & 7) * 4;
  const int k0 = blockIdx.x * 32, c0 = blockIdx.y * 32;
  const unsigned short* qb = qkvT + (size_t)blockIdx.z * S_DIM * (3 * U_DIM);
  ushort4 v = *(const ushort4*)(qb + (size_t)(k0 + r) * (3 * U_DIM) + 2 * U_DIM + c0 + c4);
  T[r][c4 + 0] = v.x; T[r][c4 + 1] = v.y; T[r][c4 + 2] = v.z; T[r][c4 + 3] = v.w;
  __syncthreads();
  ushort4 o;
  o.x = T[c4 + 0][r]; o.y = T[c4 + 1][r]; o.z = T[c4 + 2][r]; o.w = T[c4 + 3][r];
  *(ushort4*)(VT + (size_t)blockIdx.z * U_DIM * S_DIM + (size_t)(c0 + r) * S_DIM + k0 + c4) = o;
}

// ---------------------------------------------------------------------------
// 256x256 tile, BK=32, 3-slot rotating LDS pipeline GEMM (counted vmcnt).
//   D[m][n] = sum_k A[m][k]*B[n][k]; A,B row-major K=1024 contiguous.
// 512 thr / 8 waves (2M x 4N), per-wave C = 128x64, 32 indep MFMA / K-tile.
// While computing tile t (slot t%3) we stage tile t+2 (slot (t+2)%3) whose
// readers finished at the end-of-(t-1) barrier => race-free with ONE barrier
// + s_waitcnt vmcnt(4) per K-tile; loads stay in flight across barriers.
// Slots are separate __shared__ objects (unroll x3) so the waitcnt pass
// can't alias staging against current-slot ds_reads.
// ---------------------------------------------------------------------------
__device__ __forceinline__ void g256_stage(const unsigned short* pA0, const unsigned short* pA1,
                                           const unsigned short* pB0, const unsigned short* pB1,
                                           int k0, int tid,
                                           unsigned short* dA, unsigned short* dB) {
  gll16(pA0 + k0, dA + (size_t)tid * 8);
  gll16(pB0 + k0, dB + (size_t)tid * 8);
  gll16(pA1 + k0, dA + (size_t)(512 + tid) * 8);
  gll16(pB1 + k0, dB + (size_t)(512 + tid) * 8);
}

__device__ __forceinline__ void g256_tile(const unsigned short* sa, const unsigned short* sb,
                                          int wm, int wn, int l15, int quad, f32x4 acc[8][4]) {
  s16x8 af[8], bf[4];
#pragma unroll
  for (int i = 0; i < 8; ++i) {
    int r = wm * 128 + i * 16 + l15;
    af[i] = *(const s16x8*)&sa[r * 32 + ((quad ^ ((r >> 1) & 3)) * 8)];
  }
#pragma unroll
  for (int j = 0; j < 4; ++j) {
    int r = wn * 64 + j * 16 + l15;
    bf[j] = *(const s16x8*)&sb[r * 32 + ((quad ^ ((r >> 1) & 3)) * 8)];
  }
  __builtin_amdgcn_s_setprio(1);
#pragma unroll
  for (int i = 0; i < 8; ++i)
#pragma unroll
    for (int j = 0; j < 4; ++j) acc[i][j] = MFMA16(af[i], bf[j], acc[i][j]);
  __builtin_amdgcn_s_setprio(0);
}

template <typename OUT>
__global__ __launch_bounds__(512, 2) void gemm256(const unsigned short* __restrict__ A,
                                                  const unsigned short* __restrict__ Bm,
                                                  OUT* __restrict__ D,
                                                  long long sAb, long long sBb, long long sDb,
                                                  int N) {
  __shared__ unsigned short sA0[256 * 32], sA1[256 * 32], sA2[256 * 32];
  __shared__ unsigned short sB0[256 * 32], sB1[256 * 32], sB2[256 * 32];
  const int tid = threadIdx.x;
  const int wave = tid >> 6, lane = tid & 63;
  const int l15 = lane & 15, quad = lane >> 4;
  const int wm = wave >> 2, wn = wave & 3;
  // bijective XCD swizzle (nwg % 8 == 0 at all call sites)
  const unsigned int Lb = blockIdx.x + gridDim.x * (blockIdx.y + gridDim.y * blockIdx.z);
  const unsigned int nwg = gridDim.x * gridDim.y * gridDim.z;
  const unsigned int logical = (Lb & 7u) * (nwg >> 3) + (Lb >> 3);
  const int bx = logical % gridDim.x;
  const unsigned int rem = logical / gridDim.x;
  const int by = rem % gridDim.y;
  const int bz = rem / gridDim.y;
  const int m0 = by * 256, n0 = bx * 256;
  A += (size_t)bz * sAb + (size_t)m0 * KD;
  Bm += (size_t)bz * sBb + (size_t)n0 * KD;
  D += (size_t)bz * sDb;

  // per-thread staging coords: chunk g=(pass*512+tid) -> row=g>>2, kcL=g&3,
  // source kc = kcL ^ ((row>>1)&3)  (same involution applied on ds_read)
  const int g0 = tid, g1 = 512 + tid;
  const int rA0 = g0 >> 2, rA1 = g1 >> 2;
  const int kc0 = (g0 & 3) ^ ((rA0 >> 1) & 3), kc1 = (g1 & 3) ^ ((rA1 >> 1) & 3);
  const unsigned short* pA0 = A + (size_t)rA0 * KD + kc0 * 8;
  const unsigned short* pA1 = A + (size_t)rA1 * KD + kc1 * 8;
  const unsigned short* pB0 = Bm + (size_t)rA0 * KD + kc0 * 8;
  const unsigned short* pB1 = Bm + (size_t)rA1 * KD + kc1 * 8;

  f32x4 acc[8][4] = {};

  // prologue: tiles 0,1 in flight; wait tile 0 (allow tile 1's 4 loads)
  g256_stage(pA0, pA1, pB0, pB1, 0, tid, sA0, sB0);
  g256_stage(pA0, pA1, pB0, pB1, 32, tid, sA1, sB1);
  asm volatile("s_waitcnt vmcnt(4)" ::: "memory");
  __builtin_amdgcn_s_barrier();

#define G256_STEP(T, SAc, SBc, SAn, SBn, DO_STAGE, WAITN)                      \
  {                                                                            \
    if (DO_STAGE) g256_stage(pA0, pA1, pB0, pB1, ((T) + 2) * 32, tid, SAn, SBn); \
    g256_tile(SAc, SBc, wm, wn, l15, quad, acc);                               \
    if ((WAITN) >= 0) {                                                        \
      if ((WAITN) == 4) asm volatile("s_waitcnt vmcnt(4)" ::: "memory");       \
      else asm volatile("s_waitcnt vmcnt(0)" ::: "memory");                    \
      __builtin_amdgcn_s_barrier();                                            \
    }                                                                          \
  }

  // steady state: tiles 0..29 (slot = t%3), staging t+2 two tiles ahead
  for (int tt = 0; tt < 30; tt += 3) {
    G256_STEP(tt + 0, sA0, sB0, sA2, sB2, 1, 4);
    G256_STEP(tt + 1, sA1, sB1, sA0, sB0, 1, 4);
    G256_STEP(tt + 2, sA2, sB2, sA1, sB1, 1, 4);
  }
  // tail: tile 30 (no stage, drain for tile 31), tile 31 (no barrier after)
  G256_STEP(30, sA0, sB0, sA2, sB2, 0, 0);
  G256_STEP(31, sA1, sB1, sA2, sB2, 0, -1);
#undef G256_STEP

#pragma unroll
  for (int i = 0; i < 8; ++i)
#pragma unroll
    for (int j = 0; j < 4; ++j) {
      f32x4 v = acc[i][j];
#pragma unroll
      for (int r = 0; r < 4; ++r) {
        int m = m0 + wm * 128 + i * 16 + quad * 4 + r;
        int n = n0 + wn * 64 + j * 16 + l15;
        if constexpr (sizeof(OUT) == 2) D[(size_t)m * N + n] = f2bf(v[r]);
        else D[(size_t)m * N + n] = v[r];
      }
    }
}

// ---------------------------------------------------------------------------
// Fused masked-relu attention, 2-barrier pipelined K-loop (unchanged R1).
// ---------------------------------------------------------------------------
__global__ __launch_bounds__(256, 2) void attn_mfma(const unsigned short* __restrict__ qkvT,
                                                    const unsigned short* __restrict__ VT,
                                                    const unsigned long long* __restrict__ bits,
                                                    const float* __restrict__ invm,
                                                    unsigned short* __restrict__ CcT, int b0) {
  __shared__ unsigned short QV[64 * 128];  // Q staging, then V ping buf (16 KB)
  __shared__ unsigned short Ks[64 * 128];  // [k][c] swizzled (16 KB)
  __shared__ unsigned short Vs[128 * 64];  // [c][k] swizzled (16 KB)
  __shared__ unsigned short Ps[64 * 64];   // [q][k] swizzled (8 KB)
  __shared__ float invs[64];

  const int tid = threadIdx.x, wave = tid >> 6, lane = tid & 63;
  const int l15 = lane & 15, quad = lane >> 4;
  // bijective XCD swizzle: nwg = 128*gridDim.z, always % 8 == 0.
  const int L = blockIdx.x + 16 * (blockIdx.y + 8 * blockIdx.z);
  const int cpx = (16 * H_DIM * gridDim.z) >> 3;
  const int logical = (L & 7) * cpx + (L >> 3);
  const int qt = logical & 15, h = (logical >> 4) & 7, z = logical >> 7;
  const int q0 = qt * 64, b = b0 + z;
  const unsigned short* qB = qkvT + (size_t)z * S_DIM * (3 * U_DIM);
  const unsigned short* Vb = VT + (size_t)z * U_DIM * S_DIM + (size_t)h * C_DIM * S_DIM;

  // prologue: stage Q -> QV, K(0) -> Ks, V(0) -> Vs
#pragma unroll
  for (int t = 0; t < 4; ++t) {
    int p = wave * 256 + t * 64 + lane;
    int row = p >> 4, c = (p & 15) ^ (row & 7);
    gll16(qB + (size_t)(q0 + row) * (3 * U_DIM) + h * C_DIM + c * 8,
          &QV[(wave * 256 + t * 64) * 8]);
    gll16(qB + (size_t)(row) * (3 * U_DIM) + U_DIM + h * C_DIM + c * 8,
          &Ks[(wave * 256 + t * 64) * 8]);
    int vrow = p >> 3, vkc = (p & 7) ^ (vrow & 7);
    gll16(Vb + (size_t)vrow * S_DIM + vkc * 8, &Vs[(wave * 256 + t * 64) * 8]);
  }
  if (tid < 64) invs[tid] = invm[(size_t)b * S_DIM + q0 + tid];
  __syncthreads();

  s16x8 qf[4][4];
#pragma unroll
  for (int j = 0; j < 4; ++j)
#pragma unroll
    for (int kk = 0; kk < 4; ++kk) {
      int row = j * 16 + l15;
      qf[j][kk] = *(const s16x8*)&QV[row * 128 + ((kk * 4 + quad) ^ (row & 7)) * 8];
    }
  float invf[4];
#pragma unroll
  for (int j = 0; j < 4; ++j) invf[j] = invs[j * 16 + l15];

  f32x4 pacc[4][2] = {};

  for (int kt = 0; kt < S_DIM / 64; ++kt) {
    unsigned long long w64[4];
    {
      const unsigned long long* mw =
          bits + (size_t)kt * (B_DIM * S_DIM) + (size_t)b * S_DIM + q0;
#pragma unroll
      for (int j = 0; j < 4; ++j) w64[j] = mw[j * 16 + l15];
    }

    // scores D[k][q]: wave handles k rows [wave*16, wave*16+16), all 64 q
    s16x8 af[4];
#pragma unroll
    for (int kk = 0; kk < 4; ++kk) {
      int row = wave * 16 + l15;
      af[kk] = *(const s16x8*)&Ks[row * 128 + ((kk * 4 + quad) ^ (row & 7)) * 8];
    }
    f32x4 sacc[4] = {};
    __builtin_amdgcn_s_setprio(1);
#pragma unroll
    for (int kk = 0; kk < 4; ++kk)
#pragma unroll
      for (int j = 0; j < 4; ++j) sacc[j] = MFMA16(af[kk], qf[j][kk], sacc[j]);
    __builtin_amdgcn_s_setprio(0);

    // P = maskbit * relu(s) * scale/m -> packed bf16 via v_cvt_pk_bf16_f32
#pragma unroll
    for (int j = 0; j < 4; ++j) {
      const unsigned int m4 = (unsigned int)(w64[j] >> (wave * 16 + quad * 4)) & 0xFu;
      float p[4];
#pragma unroll
      for (int r = 0; r < 4; ++r) {
        float t = fmaxf(sacc[j][r], 0.f) * invf[j];
        p[r] = ((m4 >> r) & 1u) ? t : 0.f;
      }
      unsigned int pk0, pk1;
      asm("v_cvt_pk_bf16_f32 %0, %1, %2" : "=v"(pk0) : "v"(p[0]), "v"(p[1]));
      asm("v_cvt_pk_bf16_f32 %0, %1, %2" : "=v"(pk1) : "v"(p[2]), "v"(p[3]));
      int q = j * 16 + l15;
      int chunk = (wave * 2 + (quad >> 1)) ^ (q & 7);
      *(uint2*)&Ps[q * 64 + chunk * 8 + (quad & 1) * 4] = make_uint2(pk0, pk1);
    }
    __syncthreads();  // P ready; all waves done reading Ks (and QV on kt==0)

    // overlap: stage K(t+1)->Ks, V(t+1)->other buf while PV computes
    if (kt < S_DIM / 64 - 1) {
      const int kn = (kt + 1) * 64;
      unsigned short* vdst = (kt & 1) ? Vs : QV;
#pragma unroll
      for (int t = 0; t < 4; ++t) {
        int p = wave * 256 + t * 64 + lane;
        int row = p >> 4, c = (p & 15) ^ (row & 7);
        gll16(qB + (size_t)(kn + row) * (3 * U_DIM) + U_DIM + h * C_DIM + c * 8,
              &Ks[(wave * 256 + t * 64) * 8]);
        int vrow = p >> 3, vkc = (p & 7) ^ (vrow & 7);
        gll16(Vb + (size_t)vrow * S_DIM + kn + vkc * 8, &vdst[(wave * 256 + t * 64) * 8]);
      }
    }

    // PV from V(kt) (even -> Vs, odd -> QV): wave c-cols [wave*32, +32)
    const unsigned short* vbuf = (kt & 1) ? QV : Vs;
#pragma unroll
    for (int ks = 0; ks < 2; ++ks) {
      s16x8 pf[4], vf[2];
#pragma unroll
      for (int i = 0; i < 4; ++i) {
        int row = i * 16 + l15;
        pf[i] = *(const s16x8*)&Ps[row * 64 + ((ks * 4 + quad) ^ (row & 7)) * 8];
      }
#pragma unroll
      for (int j = 0; j < 2; ++j) {
        int row = wave * 32 + j * 16 + l15;
        vf[j] = *(const s16x8*)&vbuf[row * 64 + ((ks * 4 + quad) ^ (row & 7)) * 8];
      }
      __builtin_amdgcn_s_setprio(1);
#pragma unroll
      for (int i = 0; i < 4; ++i)
#pragma unroll
        for (int j = 0; j < 2; ++j) pacc[i][j] = MFMA16(pf[i], vf[j], pacc[i][j]);
      __builtin_amdgcn_s_setprio(0);
    }
    __syncthreads();  // PV done + staging drained (vmcnt(0) at barrier)
  }

  // epilogue: CcT[b][q][h*128+c] bf16
  unsigned short* cb = CcT + (size_t)z * S_DIM * U_DIM;
#pragma unroll
  for (int i = 0; i < 4; ++i)
#pragma unroll
    for (int j = 0; j < 2; ++j) {
      f32x4 v = pacc[i][j];
#pragma unroll
      for (int r = 0; r < 4; ++r) {
        int q = q0 + i * 16 + quad * 4 + r;
        int c = h * C_DIM + wave * 32 + j * 16 + l15;
        cb[(size_t)q * U_DIM + c] = f2bf(v[r]);
      }
    }
}

// ---------------------------------------------------------------------------
extern "C" void kernel_launch(void* const* d_in, const int* in_sizes, int n_in,
                              void* d_out, int out_size, void* d_ws, size_t ws_size,
                              hipStream_t stream) {
  const float* x = (const float*)d_in[0];
  const unsigned char* mask_raw = (const unsigned char*)d_in[1];
  const float* w_qkv = (const float*)d_in[2];
  const float* w_out = (const float*)d_in[3];
  float* out = (float*)d_out;

  char* ws = (char*)d_ws;
  int* flag = (int*)ws;                                  // 256 B
  float* invm = (float*)(ws + 256);                      // 64 KB
  unsigned long long* bits = (unsigned long long*)(ws + 256 + 65536);  // 2 MB
  unsigned short* wqkv_bf = (unsigned short*)((char*)bits + (size_t)B_DIM * S_DIM * 16 * 8);
  unsigned short* wout_bf = (unsigned short*)((char*)wqkv_bf + (size_t)3 * U_DIM * U_DIM * 2);
  char* heap = (char*)wout_bf + (size_t)U_DIM * U_DIM * 2;

  const size_t xT_pb = (size_t)U_DIM * S_DIM * 2;
  const size_t qkvT_pb = (size_t)3 * U_DIM * S_DIM * 2;
  const size_t vT_pb = (size_t)U_DIM * S_DIM * 2;
  const size_t ccT_pb = (size_t)U_DIM * S_DIM * 2;
  const size_t per_batch = xT_pb + qkvT_pb + vT_pb + ccT_pb;  // 12.58 MB
  const size_t fixed = (size_t)(heap - ws);
  int nb = (ws_size > fixed) ? (int)((ws_size - fixed) / per_batch) : 1;
  if (nb < 1) nb = 1;
  if (nb > B_DIM) nb = B_DIM;

  unsigned short* xT = (unsigned short*)heap;
  unsigned short* qkvT = (unsigned short*)(heap + (size_t)nb * xT_pb);
  unsigned short* VT = (unsigned short*)(heap + (size_t)nb * (xT_pb + qkvT_pb));
  unsigned short* CcT = (unsigned short*)(heap + (size_t)nb * (xT_pb + qkvT_pb + vT_pb));

  detect_mask<<<1, 256, 0, stream>>>(mask_raw, flag);
  pack_mask<<<dim3(S_DIM / 64, S_DIM / 64, B_DIM), 256, 0, stream>>>(mask_raw, flag, bits);
  invm_from_bits<<<(B_DIM * S_DIM) / 256, 256, 0, stream>>>(bits, invm);
  cvt_bf16<<<(3 * U_DIM * U_DIM) / 1024, 256, 0, stream>>>(w_qkv, wqkv_bf, 3 * U_DIM * U_DIM);
  cvt_bf16<<<(U_DIM * U_DIM) / 1024, 256, 0, stream>>>(w_out, wout_bf, U_DIM * U_DIM);

  for (int b0 = 0; b0 < B_DIM; b0 += nb) {
    int cnt = (B_DIM - b0 < nb) ? (B_DIM - b0) : nb;
    transpose_x<<<dim3(S_DIM / 32, U_DIM / 32, cnt), 256, 0, stream>>>(
        x + (size_t)b0 * U_DIM * S_DIM, xT);
    gemm256<unsigned short><<<dim3(3 * U_DIM / 256, S_DIM / 256, cnt), 512, 0, stream>>>(
        xT, wqkv_bf, qkvT, (long long)U_DIM * S_DIM, 0LL, (long long)3 * U_DIM * S_DIM, 3 * U_DIM);
    transpose_v<<<dim3(S_DIM / 32, U_DIM / 32, cnt), 256, 0, stream>>>(qkvT, VT);
    attn_mfma<<<dim3(S_DIM / 64, H_DIM, cnt), 256, 0, stream>>>(
        qkvT, VT, bits, invm, CcT, b0);
    gemm256<float><<<dim3(S_DIM / 256, U_DIM / 256, cnt), 512, 0, stream>>>(
        wout_bf, CcT, out + (size_t)b0 * U_DIM * S_DIM, 0LL,
        (long long)U_DIM * S_DIM, (long long)U_DIM * S_DIM, S_DIM);
  }
}

// Round 3
// 462.007 us; speedup vs baseline: 1.0492x; 1.0065x over previous
//
#include <hip/hip_runtime.h>

#define B_DIM 16
#define U_DIM 1024
#define H_DIM 8
#define S_DIM 1024
#define C_DIM 128
#define KD 1024  // K depth of both projection GEMMs
#define SCALE 0.08838834764831845f  // 1/sqrt(128)

typedef __attribute__((ext_vector_type(8))) short s16x8;
typedef __attribute__((ext_vector_type(4))) float f32x4;

__device__ __forceinline__ void gll16(const void* g, void* l) {
  __builtin_amdgcn_global_load_lds(
      (const __attribute__((address_space(1))) unsigned int*)g,
      (__attribute__((address_space(3))) unsigned int*)l, 16, 0, 0);
}
__device__ __forceinline__ unsigned short f2bf(float f) {
  unsigned u = __float_as_uint(f);
  u += 0x7FFF + ((u >> 16) & 1u);
  return (unsigned short)(u >> 16);
}
#define MFMA16(a, b, c) __builtin_amdgcn_mfma_f32_16x16x32_bf16(a, b, c, 0, 0, 0)

// ---------------------------------------------------------------------------
// Mask storage detection (bool may arrive as u8 / i32 / f32).
// ---------------------------------------------------------------------------
__global__ void detect_mask(const unsigned char* __restrict__ mask_raw, int* __restrict__ flag) {
  __shared__ int not01, notf;
  if (threadIdx.x == 0) { not01 = 0; notf = 0; }
  __syncthreads();
  const unsigned int* p = (const unsigned int*)mask_raw;
  int l01 = 0, lf = 0;
  for (int i = threadIdx.x; i < 4096; i += 256) {
    unsigned int v = p[i];
    if (v != 0u && v != 1u) l01 = 1;
    if (v != 0u && v != 0x3F800000u) lf = 1;
  }
  if (l01) atomicOr(&not01, 1);
  if (lf) atomicOr(&notf, 1);
  __syncthreads();
  if (threadIdx.x == 0) flag[0] = (!not01) ? 0 : ((!notf) ? 2 : 1);
}

// ---------------------------------------------------------------------------
// Pack mask into k-major bit-words: bits[kt][b][q], word = 64 k bits.
// ---------------------------------------------------------------------------
__global__ __launch_bounds__(256) void pack_mask(const unsigned char* __restrict__ mask_raw,
                                                 const int* __restrict__ flag,
                                                 unsigned long long* __restrict__ bits) {
  __shared__ unsigned char tile[64][80];  // [q][k], pad 80 keeps 16B alignment
  const int t = threadIdx.x;
  const int kt = blockIdx.x * 64, qw = blockIdx.y, b = blockIdx.z;
  const int mk = flag[0];
  const int q = t >> 2, kbase = (t & 3) * 16;
  const size_t row = (size_t)(b * S_DIM + qw * 64 + q);
  if (mk == 1) {
    uint4 v = *(const uint4*)(mask_raw + (row << 10) + kt + kbase);
    *(uint4*)&tile[q][kbase] = v;
  } else if (mk == 0) {
    const int* p = (const int*)mask_raw + (row << 10) + kt + kbase;
#pragma unroll
    for (int j = 0; j < 4; ++j) {
      int4 v = ((const int4*)p)[j];
      uchar4 o;
      o.x = v.x ? 1 : 0; o.y = v.y ? 1 : 0; o.z = v.z ? 1 : 0; o.w = v.w ? 1 : 0;
      *(uchar4*)&tile[q][kbase + j * 4] = o;
    }
  } else {
    const float* p = (const float*)mask_raw + (row << 10) + kt + kbase;
#pragma unroll
    for (int j = 0; j < 4; ++j) {
      float4 v = ((const float4*)p)[j];
      uchar4 o;
      o.x = (v.x != 0.f) ? 1 : 0; o.y = (v.y != 0.f) ? 1 : 0;
      o.z = (v.z != 0.f) ? 1 : 0; o.w = (v.w != 0.f) ? 1 : 0;
      *(uchar4*)&tile[q][kbase + j * 4] = o;
    }
  }
  __syncthreads();
  const int wave = t >> 6, lane = t & 63;
#pragma unroll
  for (int qq = 0; qq < 16; ++qq) {
    int qr = wave * 16 + qq;
    unsigned long long bal = __ballot(tile[qr][lane] != 0);
    if (lane == 0)
      bits[(size_t)blockIdx.x * (B_DIM * S_DIM) + (size_t)b * S_DIM + qw * 64 + qr] = bal;
  }
}

// invm from packed bits: rowsum = sum_kt popcount(bits[kt][b][q])
__global__ __launch_bounds__(256) void invm_from_bits(const unsigned long long* __restrict__ bits,
                                                      float* __restrict__ invm) {
  int idx = blockIdx.x * 256 + threadIdx.x;  // = b*S + q
  int s = 0;
#pragma unroll
  for (int kt = 0; kt < S_DIM / 64; ++kt)
    s += __popcll(bits[(size_t)kt * (B_DIM * S_DIM) + idx]);
  invm[idx] = (s > 0) ? (SCALE / (float)s) : 0.f;
}

// fp32 -> bf16 elementwise (weights)
__global__ __launch_bounds__(256) void cvt_bf16(const float* __restrict__ in,
                                                unsigned short* __restrict__ out, int n) {
  int i = (blockIdx.x * 256 + threadIdx.x) * 4;
  if (i < n) {
    float4 v = *(const float4*)(in + i);
    ushort4 o;
    o.x = f2bf(v.x); o.y = f2bf(v.y); o.z = f2bf(v.z); o.w = f2bf(v.w);
    *(ushort4*)(out + i) = o;
  }
}

// x[b][u][s] f32 -> xT[b][s][u] bf16   (32x32 tiles)
__global__ __launch_bounds__(256) void transpose_x(const float* __restrict__ x,
                                                   unsigned short* __restrict__ xT) {
  __shared__ float T[32][33];
  const int t = threadIdx.x, r = t >> 3, c4 = (t & 7) * 4;
  const int s0 = blockIdx.x * 32, u0 = blockIdx.y * 32;
  const size_t base = (size_t)blockIdx.z * U_DIM * S_DIM;
  float4 v = *(const float4*)(x + base + (size_t)(u0 + r) * S_DIM + s0 + c4);
  T[r][c4 + 0] = v.x; T[r][c4 + 1] = v.y; T[r][c4 + 2] = v.z; T[r][c4 + 3] = v.w;
  __syncthreads();
  ushort4 o;
  o.x = f2bf(T[c4 + 0][r]); o.y = f2bf(T[c4 + 1][r]);
  o.z = f2bf(T[c4 + 2][r]); o.w = f2bf(T[c4 + 3][r]);
  *(ushort4*)(xT + base + (size_t)(s0 + r) * U_DIM + u0 + c4) = o;
}

// qkvT[b][k][2048+c] bf16 -> VT[b][c][k] bf16  (32x32 tiles)
__global__ __launch_bounds__(256) void transpose_v(const unsigned short* __restrict__ qkvT,
                                                   unsigned short* __restrict__ VT) {
  __shared__ unsigned short T[32][34];
  const int t = threadIdx.x, r = t >> 3, c4 = (t & 7) * 4;
  const int k0 = blockIdx.x * 32, c0 = blockIdx.y * 32;
  const unsigned short* qb = qkvT + (size_t)blockIdx.z * S_DIM * (3 * U_DIM);
  ushort4 v = *(const ushort4*)(qb + (size_t)(k0 + r) * (3 * U_DIM) + 2 * U_DIM + c0 + c4);
  T[r][c4 + 0] = v.x; T[r][c4 + 1] = v.y; T[r][c4 + 2] = v.z; T[r][c4 + 3] = v.w;
  __syncthreads();
  ushort4 o;
  o.x = T[c4 + 0][r]; o.y = T[c4 + 1][r]; o.z = T[c4 + 2][r]; o.w = T[c4 + 3][r];
  *(ushort4*)(VT + (size_t)blockIdx.z * U_DIM * S_DIM + (size_t)(c0 + r) * S_DIM + k0 + c4) = o;
}

// ---------------------------------------------------------------------------
// 256x256 tile, BK=64, double-buffered 4-phase K-loop with counted vmcnt
// (m201-style T3+T4).  D[m][n] = sum_k A[m][k]*B[n][k]; A,B row-major K=1024.
// 512 thr / 8 waves: wm = wave&3 owns 64 A-rows, wn = wave>>2 owns 128 B-cols.
// Staging units (16 KB, 2 gll16/thread): U0=A[0:128), U1=A[128:256),
//   U2=B rows {0:64,128:192}, U3=B rows {64:128,192:256}.
// Phase p of tile t stages unit p of tile t+1 (leads 4/3/2/3 phases).
// A-frags read once per tile (phase 0, 8 ds_read), held in regs; phase p
// reads j-pair {2p,2p+1} of B (4 ds_read) + 16 MFMA under setprio.
// Waits: W0 (tile start) vmcnt(2) -> U0..U2 landed, U3 in flight;
//        W1 (before phase 2) vmcnt(4) -> U3 landed, next U0/U1 in flight.
// vmcnt(0) only at the last tile. 2 barriers per K-tile.
// Safety: every stage-issue into buf^1 is separated from the last read of
// that region (previous use of buf^1, tile t-1) by the W0/W1 barriers.
// ---------------------------------------------------------------------------
template <typename OUT>
__global__ __launch_bounds__(512, 2) void gemm256(const unsigned short* __restrict__ A,
                                                  const unsigned short* __restrict__ Bm,
                                                  OUT* __restrict__ D,
                                                  long long sAb, long long sBb, long long sDb,
                                                  int N) {
  __shared__ unsigned short sA0[256 * 64], sB0[256 * 64];
  __shared__ unsigned short sA1[256 * 64], sB1[256 * 64];
  const int tid = threadIdx.x;
  const int wave = tid >> 6, lane = tid & 63;
  const int l15 = lane & 15, quad = lane >> 4;
  const int wm = wave & 3, wn = wave >> 2;
  // bijective XCD swizzle (nwg % 8 == 0 at all call sites)
  const unsigned int Lb = blockIdx.x + gridDim.x * (blockIdx.y + gridDim.y * blockIdx.z);
  const unsigned int nwg = gridDim.x * gridDim.y * gridDim.z;
  const unsigned int logical = (Lb & 7u) * (nwg >> 3) + (Lb >> 3);
  const int bx = logical % gridDim.x;
  const unsigned int rem = logical / gridDim.x;
  const int by = rem % gridDim.y;
  const int bz = rem / gridDim.y;
  const int m0 = by * 256, n0 = bx * 256;
  A += (size_t)bz * sAb + (size_t)m0 * KD;
  Bm += (size_t)bz * sBb + (size_t)n0 * KD;
  D += (size_t)bz * sDb;

  // staging coords: thread covers rows r0 / 64+r0 (pass 0/1) of each unit,
  // source chunk kc0 = (tid&7) ^ (r0&7)  (same involution on the read side)
  const int r0 = tid >> 3;                 // 0..63
  const int kc0 = (tid & 7) ^ (r0 & 7);
  const unsigned short* pA = A + (size_t)r0 * KD + kc0 * 8;
  const unsigned short* pB = Bm + (size_t)r0 * KD + kc0 * 8;
  const int wo = wave * 512;               // per-wave LDS dest base (shorts)

#define STG_U0(SA, K0)                                        \
  do {                                                        \
    gll16(pA + (K0), &(SA)[wo]);                              \
    gll16(pA + 64 * KD + (K0), &(SA)[4096 + wo]);             \
  } while (0)
#define STG_U1(SA, K0)                                        \
  do {                                                        \
    gll16(pA + 128 * KD + (K0), &(SA)[8192 + wo]);            \
    gll16(pA + 192 * KD + (K0), &(SA)[12288 + wo]);           \
  } while (0)
#define STG_U2(SB, K0)                                        \
  do {                                                        \
    gll16(pB + (K0), &(SB)[wo]);                              \
    gll16(pB + 128 * KD + (K0), &(SB)[8192 + wo]);            \
  } while (0)
#define STG_U3(SB, K0)                                        \
  do {                                                        \
    gll16(pB + 64 * KD + (K0), &(SB)[4096 + wo]);             \
    gll16(pB + 192 * KD + (K0), &(SB)[12288 + wo]);           \
  } while (0)

#define WAITB(VN)                                             \
  do {                                                        \
    asm volatile("s_waitcnt vmcnt(" #VN ")" ::: "memory");    \
    __builtin_amdgcn_s_barrier();                             \
    asm volatile("" ::: "memory");                            \
  } while (0)

  s16x8 a[4][2];
  f32x4 acc[4][8] = {};

#define LDA(SA)                                                                         \
  do {                                                                                  \
    _Pragma("unroll") for (int i = 0; i < 4; ++i) {                                     \
      int row = wm * 64 + i * 16 + l15;                                                 \
      _Pragma("unroll") for (int ks = 0; ks < 2; ++ks)                                  \
          a[i][ks] = *(const s16x8*)&(SA)[row * 64 + (((ks * 4 + quad) ^ (row & 7)) * 8)]; \
    }                                                                                   \
  } while (0)

#define PHASE(SB, P)                                                                    \
  do {                                                                                  \
    s16x8 b[2][2];                                                                      \
    _Pragma("unroll") for (int jj = 0; jj < 2; ++jj) {                                  \
      int row = wn * 128 + ((P) * 2 + jj) * 16 + l15;                                   \
      _Pragma("unroll") for (int ks = 0; ks < 2; ++ks)                                  \
          b[jj][ks] = *(const s16x8*)&(SB)[row * 64 + (((ks * 4 + quad) ^ (row & 7)) * 8)]; \
    }                                                                                   \
    __builtin_amdgcn_s_setprio(1);                                                      \
    _Pragma("unroll") for (int ks = 0; ks < 2; ++ks)                                    \
        _Pragma("unroll") for (int i = 0; i < 4; ++i)                                   \
            _Pragma("unroll") for (int jj = 0; jj < 2; ++jj)                            \
                acc[i][(P) * 2 + jj] = MFMA16(a[i][ks], b[jj][ks], acc[i][(P) * 2 + jj]); \
    __builtin_amdgcn_s_setprio(0);                                                      \
  } while (0)

  // TILE(t): compute from (SA,SB), stage tile t+1 units into (SAn,SBn) at K1.
#define TILE(SA, SB, SAn, SBn, K1)                            \
  do {                                                        \
    WAITB(2);                                                 \
    STG_U0(SAn, K1);                                          \
    LDA(SA);                                                  \
    PHASE(SB, 0);                                             \
    STG_U1(SAn, K1);                                          \
    PHASE(SB, 1);                                             \
    WAITB(4);                                                 \
    STG_U2(SBn, K1);                                          \
    PHASE(SB, 2);                                             \
    STG_U3(SBn, K1);                                          \
    PHASE(SB, 3);                                             \
  } while (0)

  // prologue: tile 0's 4 units (8 loads in flight)
  STG_U0(sA0, 0); STG_U1(sA0, 0); STG_U2(sB0, 0); STG_U3(sB0, 0);

  // tiles 0..14 (each stages tile t+1); tile parity picks the buffer
  for (int kt = 0; kt < 14; kt += 2) {
    TILE(sA0, sB0, sA1, sB1, (kt + 1) * 64);
    TILE(sA1, sB1, sA0, sB0, (kt + 2) * 64);
  }
  TILE(sA0, sB0, sA1, sB1, 15 * 64);  // tile 14, stages tile 15

  // tile 15 (last): no staging; W1 drains fully
  {
    WAITB(2);
    LDA(sA1);
    PHASE(sB1, 0);
    PHASE(sB1, 1);
    WAITB(0);
    PHASE(sB1, 2);
    PHASE(sB1, 3);
  }
#undef TILE
#undef PHASE
#undef LDA
#undef WAITB
#undef STG_U0
#undef STG_U1
#undef STG_U2
#undef STG_U3

#pragma unroll
  for (int i = 0; i < 4; ++i)
#pragma unroll
    for (int j = 0; j < 8; ++j) {
      f32x4 v = acc[i][j];
#pragma unroll
      for (int r = 0; r < 4; ++r) {
        int m = m0 + wm * 64 + i * 16 + quad * 4 + r;
        int n = n0 + wn * 128 + j * 16 + l15;
        if constexpr (sizeof(OUT) == 2) D[(size_t)m * N + n] = f2bf(v[r]);
        else D[(size_t)m * N + n] = v[r];
      }
    }
}

// ---------------------------------------------------------------------------
// Fused masked-relu attention, 2-barrier pipelined K-loop (unchanged).
// ---------------------------------------------------------------------------
__global__ __launch_bounds__(256, 2) void attn_mfma(const unsigned short* __restrict__ qkvT,
                                                    const unsigned short* __restrict__ VT,
                                                    const unsigned long long* __restrict__ bits,
                                                    const float* __restrict__ invm,
                                                    unsigned short* __restrict__ CcT, int b0) {
  __shared__ unsigned short QV[64 * 128];  // Q staging, then V ping buf (16 KB)
  __shared__ unsigned short Ks[64 * 128];  // [k][c] swizzled (16 KB)
  __shared__ unsigned short Vs[128 * 64];  // [c][k] swizzled (16 KB)
  __shared__ unsigned short Ps[64 * 64];   // [q][k] swizzled (8 KB)
  __shared__ float invs[64];

  const int tid = threadIdx.x, wave = tid >> 6, lane = tid & 63;
  const int l15 = lane & 15, quad = lane >> 4;
  // bijective XCD swizzle: nwg = 128*gridDim.z, always % 8 == 0.
  const int L = blockIdx.x + 16 * (blockIdx.y + 8 * blockIdx.z);
  const int cpx = (16 * H_DIM * gridDim.z) >> 3;
  const int logical = (L & 7) * cpx + (L >> 3);
  const int qt = logical & 15, h = (logical >> 4) & 7, z = logical >> 7;
  const int q0 = qt * 64, b = b0 + z;
  const unsigned short* qB = qkvT + (size_t)z * S_DIM * (3 * U_DIM);
  const unsigned short* Vb = VT + (size_t)z * U_DIM * S_DIM + (size_t)h * C_DIM * S_DIM;

  // prologue: stage Q -> QV, K(0) -> Ks, V(0) -> Vs
#pragma unroll
  for (int t = 0; t < 4; ++t) {
    int p = wave * 256 + t * 64 + lane;
    int row = p >> 4, c = (p & 15) ^ (row & 7);
    gll16(qB + (size_t)(q0 + row) * (3 * U_DIM) + h * C_DIM + c * 8,
          &QV[(wave * 256 + t * 64) * 8]);
    gll16(qB + (size_t)(row) * (3 * U_DIM) + U_DIM + h * C_DIM + c * 8,
          &Ks[(wave * 256 + t * 64) * 8]);
    int vrow = p >> 3, vkc = (p & 7) ^ (vrow & 7);
    gll16(Vb + (size_t)vrow * S_DIM + vkc * 8, &Vs[(wave * 256 + t * 64) * 8]);
  }
  if (tid < 64) invs[tid] = invm[(size_t)b * S_DIM + q0 + tid];
  __syncthreads();

  s16x8 qf[4][4];
#pragma unroll
  for (int j = 0; j < 4; ++j)
#pragma unroll
    for (int kk = 0; kk < 4; ++kk) {
      int row = j * 16 + l15;
      qf[j][kk] = *(const s16x8*)&QV[row * 128 + ((kk * 4 + quad) ^ (row & 7)) * 8];
    }
  float invf[4];
#pragma unroll
  for (int j = 0; j < 4; ++j) invf[j] = invs[j * 16 + l15];

  f32x4 pacc[4][2] = {};

  for (int kt = 0; kt < S_DIM / 64; ++kt) {
    unsigned long long w64[4];
    {
      const unsigned long long* mw =
          bits + (size_t)kt * (B_DIM * S_DIM) + (size_t)b * S_DIM + q0;
#pragma unroll
      for (int j = 0; j < 4; ++j) w64[j] = mw[j * 16 + l15];
    }

    // scores D[k][q]: wave handles k rows [wave*16, wave*16+16), all 64 q
    s16x8 af[4];
#pragma unroll
    for (int kk = 0; kk < 4; ++kk) {
      int row = wave * 16 + l15;
      af[kk] = *(const s16x8*)&Ks[row * 128 + ((kk * 4 + quad) ^ (row & 7)) * 8];
    }
    f32x4 sacc[4] = {};
    __builtin_amdgcn_s_setprio(1);
#pragma unroll
    for (int kk = 0; kk < 4; ++kk)
#pragma unroll
      for (int j = 0; j < 4; ++j) sacc[j] = MFMA16(af[kk], qf[j][kk], sacc[j]);
    __builtin_amdgcn_s_setprio(0);

    // P = maskbit * relu(s) * scale/m -> packed bf16 via v_cvt_pk_bf16_f32
#pragma unroll
    for (int j = 0; j < 4; ++j) {
      const unsigned int m4 = (unsigned int)(w64[j] >> (wave * 16 + quad * 4)) & 0xFu;
      float p[4];
#pragma unroll
      for (int r = 0; r < 4; ++r) {
        float t = fmaxf(sacc[j][r], 0.f) * invf[j];
        p[r] = ((m4 >> r) & 1u) ? t : 0.f;
      }
      unsigned int pk0, pk1;
      asm("v_cvt_pk_bf16_f32 %0, %1, %2" : "=v"(pk0) : "v"(p[0]), "v"(p[1]));
      asm("v_cvt_pk_bf16_f32 %0, %1, %2" : "=v"(pk1) : "v"(p[2]), "v"(p[3]));
      int q = j * 16 + l15;
      int chunk = (wave * 2 + (quad >> 1)) ^ (q & 7);
      *(uint2*)&Ps[q * 64 + chunk * 8 + (quad & 1) * 4] = make_uint2(pk0, pk1);
    }
    __syncthreads();  // P ready; all waves done reading Ks (and QV on kt==0)

    // overlap: stage K(t+1)->Ks, V(t+1)->other buf while PV computes
    if (kt < S_DIM / 64 - 1) {
      const int kn = (kt + 1) * 64;
      unsigned short* vdst = (kt & 1) ? Vs : QV;
#pragma unroll
      for (int t = 0; t < 4; ++t) {
        int p = wave * 256 + t * 64 + lane;
        int row = p >> 4, c = (p & 15) ^ (row & 7);
        gll16(qB + (size_t)(kn + row) * (3 * U_DIM) + U_DIM + h * C_DIM + c * 8,
              &Ks[(wave * 256 + t * 64) * 8]);
        int vrow = p >> 3, vkc = (p & 7) ^ (vrow & 7);
        gll16(Vb + (size_t)vrow * S_DIM + kn + vkc * 8, &vdst[(wave * 256 + t * 64) * 8]);
      }
    }

    // PV from V(kt) (even -> Vs, odd -> QV): wave c-cols [wave*32, +32)
    const unsigned short* vbuf = (kt & 1) ? QV : Vs;
#pragma unroll
    for (int ks = 0; ks < 2; ++ks) {
      s16x8 pf[4], vf[2];
#pragma unroll
      for (int i = 0; i < 4; ++i) {
        int row = i * 16 + l15;
        pf[i] = *(const s16x8*)&Ps[row * 64 + ((ks * 4 + quad) ^ (row & 7)) * 8];
      }
#pragma unroll
      for (int j = 0; j < 2; ++j) {
        int row = wave * 32 + j * 16 + l15;
        vf[j] = *(const s16x8*)&vbuf[row * 64 + ((ks * 4 + quad) ^ (row & 7)) * 8];
      }
      __builtin_amdgcn_s_setprio(1);
#pragma unroll
      for (int i = 0; i < 4; ++i)
#pragma unroll
        for (int j = 0; j < 2; ++j) pacc[i][j] = MFMA16(pf[i], vf[j], pacc[i][j]);
      __builtin_amdgcn_s_setprio(0);
    }
    __syncthreads();  // PV done + staging drained (vmcnt(0) at barrier)
  }

  // epilogue: CcT[b][q][h*128+c] bf16
  unsigned short* cb = CcT + (size_t)z * S_DIM * U_DIM;
#pragma unroll
  for (int i = 0; i < 4; ++i)
#pragma unroll
    for (int j = 0; j < 2; ++j) {
      f32x4 v = pacc[i][j];
#pragma unroll
      for (int r = 0; r < 4; ++r) {
        int q = q0 + i * 16 + quad * 4 + r;
        int c = h * C_DIM + wave * 32 + j * 16 + l15;
        cb[(size_t)q * U_DIM + c] = f2bf(v[r]);
      }
    }
}

// ---------------------------------------------------------------------------
extern "C" void kernel_launch(void* const* d_in, const int* in_sizes, int n_in,
                              void* d_out, int out_size, void* d_ws, size_t ws_size,
                              hipStream_t stream) {
  const float* x = (const float*)d_in[0];
  const unsigned char* mask_raw = (const unsigned char*)d_in[1];
  const float* w_qkv = (const float*)d_in[2];
  const float* w_out = (const float*)d_in[3];
  float* out = (float*)d_out;

  char* ws = (char*)d_ws;
  int* flag = (int*)ws;                                  // 256 B
  float* invm = (float*)(ws + 256);                      // 64 KB
  unsigned long long* bits = (unsigned long long*)(ws + 256 + 65536);  // 2 MB
  unsigned short* wqkv_bf = (unsigned short*)((char*)bits + (size_t)B_DIM * S_DIM * 16 * 8);
  unsigned short* wout_bf = (unsigned short*)((char*)wqkv_bf + (size_t)3 * U_DIM * U_DIM * 2);
  char* heap = (char*)wout_bf + (size_t)U_DIM * U_DIM * 2;

  const size_t xT_pb = (size_t)U_DIM * S_DIM * 2;
  const size_t qkvT_pb = (size_t)3 * U_DIM * S_DIM * 2;
  const size_t vT_pb = (size_t)U_DIM * S_DIM * 2;
  const size_t ccT_pb = (size_t)U_DIM * S_DIM * 2;
  const size_t per_batch = xT_pb + qkvT_pb + vT_pb + ccT_pb;  // 12.58 MB
  const size_t fixed = (size_t)(heap - ws);
  int nb = (ws_size > fixed) ? (int)((ws_size - fixed) / per_batch) : 1;
  if (nb < 1) nb = 1;
  if (nb > B_DIM) nb = B_DIM;

  unsigned short* xT = (unsigned short*)heap;
  unsigned short* qkvT = (unsigned short*)(heap + (size_t)nb * xT_pb);
  unsigned short* VT = (unsigned short*)(heap + (size_t)nb * (xT_pb + qkvT_pb));
  unsigned short* CcT = (unsigned short*)(heap + (size_t)nb * (xT_pb + qkvT_pb + vT_pb));

  detect_mask<<<1, 256, 0, stream>>>(mask_raw, flag);
  pack_mask<<<dim3(S_DIM / 64, S_DIM / 64, B_DIM), 256, 0, stream>>>(mask_raw, flag, bits);
  invm_from_bits<<<(B_DIM * S_DIM) / 256, 256, 0, stream>>>(bits, invm);
  cvt_bf16<<<(3 * U_DIM * U_DIM) / 1024, 256, 0, stream>>>(w_qkv, wqkv_bf, 3 * U_DIM * U_DIM);
  cvt_bf16<<<(U_DIM * U_DIM) / 1024, 256, 0, stream>>>(w_out, wout_bf, U_DIM * U_DIM);

  for (int b0 = 0; b0 < B_DIM; b0 += nb) {
    int cnt = (B_DIM - b0 < nb) ? (B_DIM - b0) : nb;
    transpose_x<<<dim3(S_DIM / 32, U_DIM / 32, cnt), 256, 0, stream>>>(
        x + (size_t)b0 * U_DIM * S_DIM, xT);
    gemm256<unsigned short><<<dim3(3 * U_DIM / 256, S_DIM / 256, cnt), 512, 0, stream>>>(
        xT, wqkv_bf, qkvT, (long long)U_DIM * S_DIM, 0LL, (long long)3 * U_DIM * S_DIM, 3 * U_DIM);
    transpose_v<<<dim3(S_DIM / 32, U_DIM / 32, cnt), 256, 0, stream>>>(qkvT, VT);
    attn_mfma<<<dim3(S_DIM / 64, H_DIM, cnt), 256, 0, stream>>>(
        qkvT, VT, bits, invm, CcT, b0);
    gemm256<float><<<dim3(S_DIM / 256, U_DIM / 256, cnt), 512, 0, stream>>>(
        wout_bf, CcT, out + (size_t)b0 * U_DIM * S_DIM, 0LL,
        (long long)U_DIM * S_DIM, (long long)U_DIM * S_DIM, S_DIM);
  }
}